// Round 11
// baseline (105.848 us; speedup 1.0000x reference)
//
#include <hip/hip_runtime.h>
#include <math.h>

typedef unsigned short ushort_t;
typedef unsigned int uint_t;
typedef __attribute__((ext_vector_type(8))) short bf16x8;
typedef __attribute__((ext_vector_type(16))) float f32x16;

// Problem constants (from reference)
constexpr int Bc   = 8;
constexpr int Nn   = 4500;
constexpr int Ec   = 72000;
constexpr int D    = 128;          // IN_DIM == OUT_DIM == 128
constexpr int T    = Bc * Nn;      // 36000 total nodes
constexpr int TE   = Bc * Ec;      // 576000 total edges
constexpr float EPS = 1e-5f;

constexpr int PAD = 32;            // ints per counter line (128B): [cnt, deg]
constexpr int RST = 64;            // edata slots per node (max deg ~45)

// Prep zones: W split | cntp zero | x split
constexpr int NB_W    = 64;                    // 16384 W elems / 256
constexpr int NB_Z    = (T * PAD / 4) / 256;   // 1125 (int4 zero)
constexpr int NB_X    = (T * D / 4) / 256;     // 4500 (float4 -> 2x ushort4)
constexpr int NB_PREP = NB_W + NB_Z + NB_X;    // 5689

// gemm||edge zones
constexpr int NB_GEMM = ((T / 32) * 2 + 3) / 4;   // 563
constexpr int NB_EDGE = (TE + 255) / 256;         // 2250
constexpr int NB_GE   = NB_GEMM + NB_EDGE;        // 2813

// Workspace layout (bytes), ~60.1 MB total.
constexpr size_t WS_CNTP  = 0;            // T*PAD i32 = 4,608,000
constexpr size_t WS_EDATA = 4608000;      // T*RST int2 = 18,432,000
constexpr size_t WS_DINV  = 23040000;     // T f32 = 144,000
constexpr size_t WS_XHI   = 23184000;     // T*D bf16 = 9,216,000
constexpr size_t WS_XLO   = 32400000;     // T*D bf16 = 9,216,000
constexpr size_t WS_WHI   = 41616000;     // 128*128 bf16 = 32,768
constexpr size_t WS_WLO   = 41648768;     // 128*128 bf16 = 32,768
constexpr size_t WS_H     = 41681536;     // T*D f32 = 18,432,000

__device__ __forceinline__ ushort_t f32_to_bf16_rne(float f) {
  uint_t u = __float_as_uint(f);
  uint_t r = (u + 0x7fffu + ((u >> 16) & 1u)) >> 16;
  return (ushort_t)r;
}
__device__ __forceinline__ float bf16_to_f32(ushort_t h) {
  return __uint_as_float(((uint_t)h) << 16);
}

// ---------------------------------------------------------------------------
// Prep (zoned): [0,64) W -> bf16 hi/lo; [64,1189) zero cntp (int4);
// [1189,5689) x -> planar bf16 hi/lo.
// ---------------------------------------------------------------------------
__global__ __launch_bounds__(256) void prep_kernel(
    const float* __restrict__ W, ushort_t* __restrict__ Whi,
    ushort_t* __restrict__ Wlo, int4* __restrict__ cntp4,
    const float* __restrict__ x, ushort_t* __restrict__ xhi,
    ushort_t* __restrict__ xlo) {
  const int bid = blockIdx.x;
  if (bid < NB_W) {
    int i = bid * 256 + threadIdx.x;
    float w = W[i];
    ushort_t hi = f32_to_bf16_rne(w);
    Whi[i] = hi;
    Wlo[i] = f32_to_bf16_rne(w - bf16_to_f32(hi));
  } else if (bid < NB_W + NB_Z) {
    int i = (bid - NB_W) * 256 + threadIdx.x;
    cntp4[i] = make_int4(0, 0, 0, 0);
  } else {
    int i = (bid - NB_W - NB_Z) * 256 + threadIdx.x;   // float4 index
    float4 v = ((const float4*)x)[i];
    ushort4 hi, lo;
    hi.x = f32_to_bf16_rne(v.x); lo.x = f32_to_bf16_rne(v.x - bf16_to_f32(hi.x));
    hi.y = f32_to_bf16_rne(v.y); lo.y = f32_to_bf16_rne(v.y - bf16_to_f32(hi.y));
    hi.z = f32_to_bf16_rne(v.z); lo.z = f32_to_bf16_rne(v.z - bf16_to_f32(hi.z));
    hi.w = f32_to_bf16_rne(v.w); lo.w = f32_to_bf16_rne(v.w - bf16_to_f32(hi.w));
    ((ushort4*)xhi)[i] = hi;
    ((ushort4*)xlo)[i] = lo;
  }
}

// ---------------------------------------------------------------------------
// Zone-merged GEMM || edge pass (independent work, co-scheduled on CUs).
// Zone A (bid < 563): MFMA GEMM h = x W^T + b, split-bf16 (3 MFMAs).
//   Wave = 32 rows x 64 cols; A/B frag elem = lane&31, k = 8*(lane>>5)+j;
//   C/D col = lane&31, row = (j&3)+8*(j>>2)+4*(lane>>5).
// Zone B: edge pass — rk = atomicAdd(cnt), atomicAdd(deg, ew) on the SAME
//   padded 128B line; fixed-stride placement edata[tgt*RST+rk] = {src, ew}.
// ---------------------------------------------------------------------------
__global__ __launch_bounds__(256) void gemm_edge_kernel(
    const ushort_t* __restrict__ xhi, const ushort_t* __restrict__ xlo,
    const ushort_t* __restrict__ Whi, const ushort_t* __restrict__ Wlo,
    const float* __restrict__ bias, float* __restrict__ h,
    const int* __restrict__ ei, const float* __restrict__ em,
    int* __restrict__ cntp, int2* __restrict__ edata) {
  const int bid = blockIdx.x;
  if (bid < NB_GEMM) {
    const int g = bid * 4 + (threadIdx.x >> 6);
    if (g >= (T / 32) * 2) return;
    const int lane = threadIdx.x & 63;
    const int mt = g >> 1;
    const int nh = g & 1;
    const int m0 = mt * 32;
    const int r  = lane & 31;
    const int kh = lane >> 5;

    const size_t arow = (size_t)(m0 + r) * D + kh * 8;

    f32x16 acc[2];
#pragma unroll
    for (int n = 0; n < 2; ++n)
#pragma unroll
      for (int j = 0; j < 16; ++j) acc[n][j] = 0.f;

#pragma unroll
    for (int ks = 0; ks < 8; ++ks) {
      bf16x8 ahi = *(const bf16x8*)(xhi + arow + ks * 16);
      bf16x8 alo = *(const bf16x8*)(xlo + arow + ks * 16);
#pragma unroll
      for (int n = 0; n < 2; ++n) {
        const size_t boff = (size_t)((nh * 2 + n) * 32 + r) * D + ks * 16 + kh * 8;
        bf16x8 bhi = *(const bf16x8*)(Whi + boff);
        bf16x8 blo = *(const bf16x8*)(Wlo + boff);
        acc[n] = __builtin_amdgcn_mfma_f32_32x32x16_bf16(ahi, bhi, acc[n], 0, 0, 0);
        acc[n] = __builtin_amdgcn_mfma_f32_32x32x16_bf16(ahi, blo, acc[n], 0, 0, 0);
        acc[n] = __builtin_amdgcn_mfma_f32_32x32x16_bf16(alo, bhi, acc[n], 0, 0, 0);
      }
    }

#pragma unroll
    for (int n = 0; n < 2; ++n) {
      const int col = (nh * 2 + n) * 32 + r;
      const float bv = bias[col];
#pragma unroll
      for (int j = 0; j < 16; ++j) {
        const int mrow = m0 + (j & 3) + 8 * (j >> 2) + 4 * kh;
        h[(size_t)mrow * D + col] = acc[n][j] + bv;
      }
    }
  } else {
    int e = (bid - NB_GEMM) * 256 + threadIdx.x;
    if (e >= TE) return;
    int b  = e / Ec;
    int el = e - b * Ec;
    const int* eb = ei + b * 2 * Ec;
    int t0 = eb[Ec + el];
    if ((unsigned)t0 >= (unsigned)Nn) return;     // defensive
    int tg = t0 + b * Nn;
    float ew = em[e];
    int rk = atomicAdd(&cntp[(size_t)tg * PAD], 1);
    atomicAdd((float*)&cntp[(size_t)tg * PAD + 1], ew);   // deg, same line
    if (rk >= RST) return;                        // defensive (P ~ 0)
    int s0 = eb[el];
    int sg = s0 + b * Nn;
    if ((unsigned)s0 >= (unsigned)Nn) { sg = 0; ew = 0.f; }
    edata[(size_t)tg * RST + rk] = make_int2(sg, __float_as_int(ew));
  }
}

// ---------------------------------------------------------------------------
// dinv[i] = 1/sqrt(deg[i]+1)  (deg read from the padded counter line).
// ---------------------------------------------------------------------------
__global__ __launch_bounds__(256) void dinv_kernel(
    const int* __restrict__ cntp, float* __restrict__ dinv) {
  int i = blockIdx.x * 256 + threadIdx.x;
  if (i >= T) return;
  float deg = __int_as_float(cntp[(size_t)i * PAD + 1]);
  dinv[i] = 1.0f / sqrtf(deg + 1.0f);
}

// ---------------------------------------------------------------------------
// Fused gather + residual + LayerNorm + ReLU + mask (reads h, writes out).
// XCD-pinned: bid%8 = batch (h slice 2.3MB -> per-XCD L2). 32 lanes x float4
// per row; lane-half processes alternating slots; fold via shfl_xor(32).
// ---------------------------------------------------------------------------
__global__ __launch_bounds__(256) void gather_ln_kernel(
    const float* __restrict__ h, const int* __restrict__ cntp,
    const int2* __restrict__ edata, const float* __restrict__ dinv,
    const float* __restrict__ gamma, const float* __restrict__ beta,
    const float* __restrict__ mask, float* __restrict__ out) {
  const int bid  = blockIdx.x;                  // 9000 = 8 * 1125
  const int wid  = threadIdx.x >> 6;
  const int node = (bid & 7) * Nn + (bid >> 3) * 4 + wid;
  const int lane = threadIdx.x & 63;
  const int f4   = lane & 31;
  const int half = lane >> 5;

  const float4* h4 = (const float4*)h;
  int cnt = cntp[(size_t)node * PAD];
  cnt = (cnt > RST) ? RST : cnt;
  const int2* row = edata + (size_t)node * RST;

  float4 hv = h4[(size_t)node * 32 + f4];

  float4 accE = make_float4(0.f, 0.f, 0.f, 0.f);
  int i = half;
  for (; i + 6 < cnt; i += 8) {
    int2 e0 = row[i];
    int2 e1 = row[i + 2];
    int2 e2 = row[i + 4];
    int2 e3 = row[i + 6];
    float c0 = dinv[e0.x] * __int_as_float(e0.y);
    float c1 = dinv[e1.x] * __int_as_float(e1.y);
    float c2 = dinv[e2.x] * __int_as_float(e2.y);
    float c3 = dinv[e3.x] * __int_as_float(e3.y);
    float4 v0 = h4[(size_t)e0.x * 32 + f4];
    float4 v1 = h4[(size_t)e1.x * 32 + f4];
    float4 v2 = h4[(size_t)e2.x * 32 + f4];
    float4 v3 = h4[(size_t)e3.x * 32 + f4];
    accE.x += v0.x * c0 + v1.x * c1 + v2.x * c2 + v3.x * c3;
    accE.y += v0.y * c0 + v1.y * c1 + v2.y * c2 + v3.y * c3;
    accE.z += v0.z * c0 + v1.z * c1 + v2.z * c2 + v3.z * c3;
    accE.w += v0.w * c0 + v1.w * c1 + v2.w * c2 + v3.w * c3;
  }
  for (; i < cnt; i += 2) {
    int2 e0 = row[i];
    float c0 = dinv[e0.x] * __int_as_float(e0.y);
    float4 v0 = h4[(size_t)e0.x * 32 + f4];
    accE.x += v0.x * c0;
    accE.y += v0.y * c0;
    accE.z += v0.z * c0;
    accE.w += v0.w * c0;
  }

  accE.x += __shfl_xor(accE.x, 32);
  accE.y += __shfl_xor(accE.y, 32);
  accE.z += __shfl_xor(accE.z, 32);
  accE.w += __shfl_xor(accE.w, 32);

  const float dt = dinv[node];
  float4 acc;
  acc.x = hv.x * (1.f + dt) + dt * accE.x;
  acc.y = hv.y * (1.f + dt) + dt * accE.y;
  acc.z = hv.z * (1.f + dt) + dt * accE.z;
  acc.w = hv.w * (1.f + dt) + dt * accE.w;

  float su = acc.x + acc.y + acc.z + acc.w;
  float ss = acc.x * acc.x + acc.y * acc.y + acc.z * acc.z + acc.w * acc.w;
#pragma unroll
  for (int o = 16; o > 0; o >>= 1) {
    su += __shfl_xor(su, o);
    ss += __shfl_xor(ss, o);
  }
  float mu  = su * (1.0f / 128.0f);
  float var = ss * (1.0f / 128.0f) - mu * mu;
  float rs  = 1.0f / sqrtf(var + EPS);
  float m   = mask[node];

  float4 g  = ((const float4*)gamma)[f4];
  float4 bb = ((const float4*)beta)[f4];
  float4 rv;
  rv.x = fmaxf((acc.x - mu) * rs * g.x + bb.x, 0.f) * m;
  rv.y = fmaxf((acc.y - mu) * rs * g.y + bb.y, 0.f) * m;
  rv.z = fmaxf((acc.z - mu) * rs * g.z + bb.z, 0.f) * m;
  rv.w = fmaxf((acc.w - mu) * rs * g.w + bb.w, 0.f) * m;
  if (half == 0) ((float4*)out)[(size_t)node * 32 + f4] = rv;
}

// ---------------------------------------------------------------------------
extern "C" void kernel_launch(void* const* d_in, const int* in_sizes, int n_in,
                              void* d_out, int out_size, void* d_ws, size_t ws_size,
                              hipStream_t stream) {
  const float* x     = (const float*)d_in[0];
  const int*   ei    = (const int*)d_in[1];
  const float* nmask = (const float*)d_in[2];
  const float* emask = (const float*)d_in[3];
  const float* W     = (const float*)d_in[4];
  const float* bias  = (const float*)d_in[5];
  const float* gamma = (const float*)d_in[6];
  const float* beta  = (const float*)d_in[7];
  float* out = (float*)d_out;

  char*     ws    = (char*)d_ws;
  int*      cntp  = (int*)     (ws + WS_CNTP);
  int2*     edata = (int2*)    (ws + WS_EDATA);
  float*    dinv  = (float*)   (ws + WS_DINV);
  ushort_t* xhi   = (ushort_t*)(ws + WS_XHI);
  ushort_t* xlo   = (ushort_t*)(ws + WS_XLO);
  ushort_t* Whi   = (ushort_t*)(ws + WS_WHI);
  ushort_t* Wlo   = (ushort_t*)(ws + WS_WLO);
  float*    h     = (float*)   (ws + WS_H);

  prep_kernel<<<NB_PREP, 256, 0, stream>>>(W, Whi, Wlo, (int4*)cntp, x, xhi, xlo);
  gemm_edge_kernel<<<NB_GE, 256, 0, stream>>>(xhi, xlo, Whi, Wlo, bias, h,
                                              ei, emask, cntp, edata);
  dinv_kernel<<<(T + 255) / 256, 256, 0, stream>>>(cntp, dinv);
  gather_ln_kernel<<<T / 4, 256, 0, stream>>>(h, cntp, edata, dinv,
                                              gamma, beta, nmask, out);
}

// Round 12
// 90.931 us; speedup vs baseline: 1.1640x; 1.1640x over previous
//
#include <hip/hip_runtime.h>
#include <math.h>

typedef unsigned short ushort_t;
typedef unsigned int uint_t;
typedef __attribute__((ext_vector_type(8))) short bf16x8;
typedef __attribute__((ext_vector_type(16))) float f32x16;

// Problem constants (from reference)
constexpr int Bc   = 8;
constexpr int Nn   = 4500;
constexpr int Ec   = 72000;
constexpr int D    = 128;          // IN_DIM == OUT_DIM == 128
constexpr int T    = Bc * Nn;      // 36000 total nodes
constexpr int TE   = Bc * Ec;      // 576000 total edges
constexpr float EPS = 1e-5f;

constexpr int PAD = 32;            // ints per counter line (128B)
constexpr int RST = 64;            // edata slots per node (max deg ~45), 4B each

// Prep zones: W split | cntp zero | x split
constexpr int NB_W    = 64;                    // 16384 W elems / 256
constexpr int NB_Z    = (T * PAD / 4) / 256;   // 1125 (int4 zero)
constexpr int NB_X    = (T * D / 4) / 256;     // 4500
constexpr int NB_PREP = NB_W + NB_Z + NB_X;    // 5689

// Edge pass: XCD-pinned, 8 batches x 282 chunks
constexpr int NB_ECH  = (Ec + 255) / 256;      // 282
constexpr int NB_EDGE = 8 * NB_ECH;            // 2256

// Workspace layout (bytes), ~50.9 MB total.
constexpr size_t WS_CNTP  = 0;            // T*PAD i32 = 4,608,000
constexpr size_t WS_EDATA = 4608000;      // T*RST u32 = 9,216,000
constexpr size_t WS_DINV  = 13824000;     // T f32 = 144,000
constexpr size_t WS_XHI   = 13968000;     // T*D bf16 = 9,216,000
constexpr size_t WS_XLO   = 23184000;     // T*D bf16 = 9,216,000
constexpr size_t WS_WHI   = 32400000;     // 128*128 bf16 = 32,768
constexpr size_t WS_WLO   = 32432768;     // 128*128 bf16 = 32,768
constexpr size_t WS_H     = 32465536;     // T*D f32 = 18,432,000

__device__ __forceinline__ ushort_t f32_to_bf16_rne(float f) {
  uint_t u = __float_as_uint(f);
  uint_t r = (u + 0x7fffu + ((u >> 16) & 1u)) >> 16;
  return (ushort_t)r;
}
__device__ __forceinline__ float bf16_to_f32(ushort_t h) {
  return __uint_as_float(((uint_t)h) << 16);
}

// ---------------------------------------------------------------------------
// Prep (zoned): [0,64) W -> bf16 hi/lo; [64,1189) zero cntp (int4);
// [1189,5689) x -> planar bf16 hi/lo.
// ---------------------------------------------------------------------------
__global__ __launch_bounds__(256) void prep_kernel(
    const float* __restrict__ W, ushort_t* __restrict__ Whi,
    ushort_t* __restrict__ Wlo, int4* __restrict__ cntp4,
    const float* __restrict__ x, ushort_t* __restrict__ xhi,
    ushort_t* __restrict__ xlo) {
  const int bid = blockIdx.x;
  if (bid < NB_W) {
    int i = bid * 256 + threadIdx.x;
    float w = W[i];
    ushort_t hi = f32_to_bf16_rne(w);
    Whi[i] = hi;
    Wlo[i] = f32_to_bf16_rne(w - bf16_to_f32(hi));
  } else if (bid < NB_W + NB_Z) {
    int i = (bid - NB_W) * 256 + threadIdx.x;
    cntp4[i] = make_int4(0, 0, 0, 0);
  } else {
    int i = (bid - NB_W - NB_Z) * 256 + threadIdx.x;   // float4 index
    float4 v = ((const float4*)x)[i];
    ushort4 hi, lo;
    hi.x = f32_to_bf16_rne(v.x); lo.x = f32_to_bf16_rne(v.x - bf16_to_f32(hi.x));
    hi.y = f32_to_bf16_rne(v.y); lo.y = f32_to_bf16_rne(v.y - bf16_to_f32(hi.y));
    hi.z = f32_to_bf16_rne(v.z); lo.z = f32_to_bf16_rne(v.z - bf16_to_f32(hi.z));
    hi.w = f32_to_bf16_rne(v.w); lo.w = f32_to_bf16_rne(v.w - bf16_to_f32(hi.w));
    ((ushort4*)xhi)[i] = hi;
    ((ushort4*)xlo)[i] = lo;
  }
}

// ---------------------------------------------------------------------------
// Edge pass (XCD-pinned: bid&7 = batch): rk = fetch-add on padded counter;
// packed placement edata[tgt*RST+rk] = bf16(ew)<<16 | src_local (4B).
// Batch's counter lines + edata rows (~1.7MB) stay in one XCD's L2.
// ---------------------------------------------------------------------------
__global__ __launch_bounds__(256) void edge_kernel(
    const int* __restrict__ ei, const float* __restrict__ em,
    int* __restrict__ cntp, uint_t* __restrict__ edata) {
  const int b  = blockIdx.x & 7;
  const int el = (blockIdx.x >> 3) * 256 + threadIdx.x;
  if (el >= Ec) return;
  const int* eb = ei + b * 2 * Ec;
  int t0 = eb[Ec + el];
  if ((unsigned)t0 >= (unsigned)Nn) return;     // defensive
  int tg = t0 + b * Nn;
  int rk = atomicAdd(&cntp[(size_t)tg * PAD], 1);
  if (rk >= RST) return;                        // defensive (P ~ 0)
  int s0 = eb[el];
  float ew = em[b * Ec + el];
  uint_t sl = (uint_t)s0;
  if ((unsigned)s0 >= (unsigned)Nn) { sl = 0; ew = 0.f; }
  uint_t pk = ((uint_t)f32_to_bf16_rne(ew) << 16) | sl;
  edata[(size_t)tg * RST + rk] = pk;
}

// ---------------------------------------------------------------------------
// dinv[i] = 1/sqrt(deg+1), deg = sum of packed bf16 ew over the node's row.
// ---------------------------------------------------------------------------
__global__ __launch_bounds__(256) void dinv_kernel(
    const uint_t* __restrict__ edata, const int* __restrict__ cntp,
    float* __restrict__ dinv) {
  int i = blockIdx.x * 256 + threadIdx.x;
  if (i >= T) return;
  int cnt = cntp[(size_t)i * PAD];
  cnt = (cnt > RST) ? RST : cnt;
  const uint_t* row = edata + (size_t)i * RST;
  float s = 0.f;
  for (int j = 0; j < cnt; ++j) s += bf16_to_f32((ushort_t)(row[j] >> 16));
  dinv[i] = 1.0f / sqrtf(s + 1.0f);
}

// ---------------------------------------------------------------------------
// MFMA GEMM: block = one 32-row tile; 4 waves = 4 col-quarters (32 cols),
// sharing the 16KB A-tile via L1. 1125 blocks. Split-bf16 (3 MFMAs).
// A/B frag: elem = lane&31, k = 8*(lane>>5)+j. C/D: col = lane&31,
// row = (j&3)+8*(j>>2)+4*(lane>>5).
// ---------------------------------------------------------------------------
__global__ __launch_bounds__(256) void gemm_kernel(
    const ushort_t* __restrict__ xhi, const ushort_t* __restrict__ xlo,
    const ushort_t* __restrict__ Whi, const ushort_t* __restrict__ Wlo,
    const float* __restrict__ bias, float* __restrict__ h) {
  const int wid  = threadIdx.x >> 6;      // col-quarter
  const int lane = threadIdx.x & 63;
  const int m0 = blockIdx.x * 32;
  const int r  = lane & 31;
  const int kh = lane >> 5;

  const size_t arow = (size_t)(m0 + r) * D + kh * 8;

  f32x16 acc;
#pragma unroll
  for (int j = 0; j < 16; ++j) acc[j] = 0.f;

#pragma unroll
  for (int ks = 0; ks < 8; ++ks) {
    bf16x8 ahi = *(const bf16x8*)(xhi + arow + ks * 16);
    bf16x8 alo = *(const bf16x8*)(xlo + arow + ks * 16);
    const size_t boff = (size_t)(wid * 32 + r) * D + ks * 16 + kh * 8;
    bf16x8 bhi = *(const bf16x8*)(Whi + boff);
    bf16x8 blo = *(const bf16x8*)(Wlo + boff);
    acc = __builtin_amdgcn_mfma_f32_32x32x16_bf16(ahi, bhi, acc, 0, 0, 0);
    acc = __builtin_amdgcn_mfma_f32_32x32x16_bf16(ahi, blo, acc, 0, 0, 0);
    acc = __builtin_amdgcn_mfma_f32_32x32x16_bf16(alo, bhi, acc, 0, 0, 0);
  }

  const int col = wid * 32 + r;
  const float bv = bias[col];
#pragma unroll
  for (int j = 0; j < 16; ++j) {
    const int mrow = m0 + (j & 3) + 8 * (j >> 2) + 4 * kh;
    h[(size_t)mrow * D + col] = acc[j] + bv;
  }
}

// ---------------------------------------------------------------------------
// Fused gather + residual + LayerNorm + ReLU + mask (packed edata).
// XCD-pinned: bid%8 = batch (h slice 2.3MB -> per-XCD L2). 32 lanes x float4
// per row; lane-half processes alternating slots; fold via shfl_xor(32).
// ---------------------------------------------------------------------------
__global__ __launch_bounds__(256) void gather_ln_kernel(
    const float* __restrict__ h, const int* __restrict__ cntp,
    const uint_t* __restrict__ edata, const float* __restrict__ dinv,
    const float* __restrict__ gamma, const float* __restrict__ beta,
    const float* __restrict__ mask, float* __restrict__ out) {
  const int bid  = blockIdx.x;                  // 9000 = 8 * 1125
  const int b    = bid & 7;
  const int wid  = threadIdx.x >> 6;
  const int node = b * Nn + (bid >> 3) * 4 + wid;
  const int bOff = b * Nn;
  const int lane = threadIdx.x & 63;
  const int f4   = lane & 31;
  const int half = lane >> 5;

  const float4* h4 = (const float4*)h;
  int cnt = cntp[(size_t)node * PAD];
  cnt = (cnt > RST) ? RST : cnt;
  const uint_t* row = edata + (size_t)node * RST;

  float4 hv = h4[(size_t)node * 32 + f4];

  float4 accE = make_float4(0.f, 0.f, 0.f, 0.f);
  int i = half;
  for (; i + 6 < cnt; i += 8) {
    uint_t p0 = row[i];
    uint_t p1 = row[i + 2];
    uint_t p2 = row[i + 4];
    uint_t p3 = row[i + 6];
    int sg0 = bOff + (p0 & 0xFFFFu);
    int sg1 = bOff + (p1 & 0xFFFFu);
    int sg2 = bOff + (p2 & 0xFFFFu);
    int sg3 = bOff + (p3 & 0xFFFFu);
    float c0 = dinv[sg0] * bf16_to_f32((ushort_t)(p0 >> 16));
    float c1 = dinv[sg1] * bf16_to_f32((ushort_t)(p1 >> 16));
    float c2 = dinv[sg2] * bf16_to_f32((ushort_t)(p2 >> 16));
    float c3 = dinv[sg3] * bf16_to_f32((ushort_t)(p3 >> 16));
    float4 v0 = h4[(size_t)sg0 * 32 + f4];
    float4 v1 = h4[(size_t)sg1 * 32 + f4];
    float4 v2 = h4[(size_t)sg2 * 32 + f4];
    float4 v3 = h4[(size_t)sg3 * 32 + f4];
    accE.x += v0.x * c0 + v1.x * c1 + v2.x * c2 + v3.x * c3;
    accE.y += v0.y * c0 + v1.y * c1 + v2.y * c2 + v3.y * c3;
    accE.z += v0.z * c0 + v1.z * c1 + v2.z * c2 + v3.z * c3;
    accE.w += v0.w * c0 + v1.w * c1 + v2.w * c2 + v3.w * c3;
  }
  for (; i < cnt; i += 2) {
    uint_t p0 = row[i];
    int sg0 = bOff + (p0 & 0xFFFFu);
    float c0 = dinv[sg0] * bf16_to_f32((ushort_t)(p0 >> 16));
    float4 v0 = h4[(size_t)sg0 * 32 + f4];
    accE.x += v0.x * c0;
    accE.y += v0.y * c0;
    accE.z += v0.z * c0;
    accE.w += v0.w * c0;
  }

  accE.x += __shfl_xor(accE.x, 32);
  accE.y += __shfl_xor(accE.y, 32);
  accE.z += __shfl_xor(accE.z, 32);
  accE.w += __shfl_xor(accE.w, 32);

  const float dt = dinv[node];
  float4 acc;
  acc.x = hv.x * (1.f + dt) + dt * accE.x;
  acc.y = hv.y * (1.f + dt) + dt * accE.y;
  acc.z = hv.z * (1.f + dt) + dt * accE.z;
  acc.w = hv.w * (1.f + dt) + dt * accE.w;

  float su = acc.x + acc.y + acc.z + acc.w;
  float ss = acc.x * acc.x + acc.y * acc.y + acc.z * acc.z + acc.w * acc.w;
#pragma unroll
  for (int o = 16; o > 0; o >>= 1) {
    su += __shfl_xor(su, o);
    ss += __shfl_xor(ss, o);
  }
  float mu  = su * (1.0f / 128.0f);
  float var = ss * (1.0f / 128.0f) - mu * mu;
  float rs  = 1.0f / sqrtf(var + EPS);
  float m   = mask[node];

  float4 g  = ((const float4*)gamma)[f4];
  float4 bb = ((const float4*)beta)[f4];
  float4 rv;
  rv.x = fmaxf((acc.x - mu) * rs * g.x + bb.x, 0.f) * m;
  rv.y = fmaxf((acc.y - mu) * rs * g.y + bb.y, 0.f) * m;
  rv.z = fmaxf((acc.z - mu) * rs * g.z + bb.z, 0.f) * m;
  rv.w = fmaxf((acc.w - mu) * rs * g.w + bb.w, 0.f) * m;
  if (half == 0) ((float4*)out)[(size_t)node * 32 + f4] = rv;
}

// ---------------------------------------------------------------------------
extern "C" void kernel_launch(void* const* d_in, const int* in_sizes, int n_in,
                              void* d_out, int out_size, void* d_ws, size_t ws_size,
                              hipStream_t stream) {
  const float* x     = (const float*)d_in[0];
  const int*   ei    = (const int*)d_in[1];
  const float* nmask = (const float*)d_in[2];
  const float* emask = (const float*)d_in[3];
  const float* W     = (const float*)d_in[4];
  const float* bias  = (const float*)d_in[5];
  const float* gamma = (const float*)d_in[6];
  const float* beta  = (const float*)d_in[7];
  float* out = (float*)d_out;

  char*     ws    = (char*)d_ws;
  int*      cntp  = (int*)     (ws + WS_CNTP);
  uint_t*   edata = (uint_t*)  (ws + WS_EDATA);
  float*    dinv  = (float*)   (ws + WS_DINV);
  ushort_t* xhi   = (ushort_t*)(ws + WS_XHI);
  ushort_t* xlo   = (ushort_t*)(ws + WS_XLO);
  ushort_t* Whi   = (ushort_t*)(ws + WS_WHI);
  ushort_t* Wlo   = (ushort_t*)(ws + WS_WLO);
  float*    h     = (float*)   (ws + WS_H);

  prep_kernel<<<NB_PREP, 256, 0, stream>>>(W, Whi, Wlo, (int4*)cntp, x, xhi, xlo);
  edge_kernel<<<NB_EDGE, 256, 0, stream>>>(ei, emask, cntp, edata);
  dinv_kernel<<<(T + 255) / 256, 256, 0, stream>>>(edata, cntp, dinv);
  gemm_kernel<<<T / 32, 256, 0, stream>>>(xhi, xlo, Whi, Wlo, bias, h);
  gather_ln_kernel<<<T / 4, 256, 0, stream>>>(h, cntp, edata, dinv,
                                              gamma, beta, nmask, out);
}

// Round 13
// 87.530 us; speedup vs baseline: 1.2093x; 1.0389x over previous
//
#include <hip/hip_runtime.h>
#include <math.h>

typedef unsigned short ushort_t;
typedef unsigned int uint_t;
typedef __attribute__((ext_vector_type(8))) short bf16x8;
typedef __attribute__((ext_vector_type(16))) float f32x16;

// Problem constants (from reference)
constexpr int Bc   = 8;
constexpr int Nn   = 4500;
constexpr int Ec   = 72000;
constexpr int D    = 128;          // IN_DIM == OUT_DIM == 128
constexpr int T    = Bc * Nn;      // 36000 total nodes
constexpr int TE   = Bc * Ec;      // 576000 total edges
constexpr float EPS = 1e-5f;

constexpr int PAD = 32;            // ints per counter line (128B)
constexpr int RST = 64;            // edata slots per node (max deg ~45), 4B each

// Prep zones: W split | cntp zero
constexpr int NB_W    = 64;                    // 16384 W elems / 256
constexpr int NB_Z    = (T * PAD / 4) / 256;   // 1125 (int4 zero)
constexpr int NB_PREP = NB_W + NB_Z;           // 1189

// Edge pass: XCD-pinned, 8 batches x 282 chunks
constexpr int NB_ECH  = (Ec + 255) / 256;      // 282
constexpr int NB_EDGE = 8 * NB_ECH;            // 2256

// GEMM: 2250 waves (32 rows x 64 cols each) -> 563 blocks
constexpr int NB_GEMM = ((T / 32) * 2 + 3) / 4;

// Workspace layout (bytes), ~32.5 MB total.
constexpr size_t WS_CNTP  = 0;            // T*PAD i32 = 4,608,000
constexpr size_t WS_EDATA = 4608000;      // T*RST u32 = 9,216,000
constexpr size_t WS_DINV  = 13824000;     // T f32 = 144,000
constexpr size_t WS_WHI   = 13968000;     // 128*128 bf16 = 32,768
constexpr size_t WS_WLO   = 14000768;     // 128*128 bf16 = 32,768
constexpr size_t WS_H     = 14033536;     // T*D f32 = 18,432,000

__device__ __forceinline__ ushort_t f32_to_bf16_rne(float f) {
  uint_t u = __float_as_uint(f);
  uint_t r = (u + 0x7fffu + ((u >> 16) & 1u)) >> 16;
  return (ushort_t)r;
}
__device__ __forceinline__ float bf16_to_f32(ushort_t h) {
  return __uint_as_float(((uint_t)h) << 16);
}

// ---------------------------------------------------------------------------
// Prep (zoned): [0,64) W -> bf16 hi/lo; [64,1189) zero cntp (int4).
// x staging round-trip removed: GEMM converts x in-register (R13).
// ---------------------------------------------------------------------------
__global__ __launch_bounds__(256) void prep_kernel(
    const float* __restrict__ W, ushort_t* __restrict__ Whi,
    ushort_t* __restrict__ Wlo, int4* __restrict__ cntp4) {
  const int bid = blockIdx.x;
  if (bid < NB_W) {
    int i = bid * 256 + threadIdx.x;
    float w = W[i];
    ushort_t hi = f32_to_bf16_rne(w);
    Whi[i] = hi;
    Wlo[i] = f32_to_bf16_rne(w - bf16_to_f32(hi));
  } else {
    int i = (bid - NB_W) * 256 + threadIdx.x;
    cntp4[i] = make_int4(0, 0, 0, 0);
  }
}

// ---------------------------------------------------------------------------
// Edge pass (XCD-pinned: bid&7 = batch): rk = fetch-add on padded counter;
// packed placement edata[tgt*RST+rk] = bf16(ew)<<16 | src_local (4B).
// ---------------------------------------------------------------------------
__global__ __launch_bounds__(256) void edge_kernel(
    const int* __restrict__ ei, const float* __restrict__ em,
    int* __restrict__ cntp, uint_t* __restrict__ edata) {
  const int b  = blockIdx.x & 7;
  const int el = (blockIdx.x >> 3) * 256 + threadIdx.x;
  if (el >= Ec) return;
  const int* eb = ei + b * 2 * Ec;
  int t0 = eb[Ec + el];
  if ((unsigned)t0 >= (unsigned)Nn) return;     // defensive
  int tg = t0 + b * Nn;
  int rk = atomicAdd(&cntp[(size_t)tg * PAD], 1);
  if (rk >= RST) return;                        // defensive (P ~ 0)
  int s0 = eb[el];
  float ew = em[b * Ec + el];
  uint_t sl = (uint_t)s0;
  if ((unsigned)s0 >= (unsigned)Nn) { sl = 0; ew = 0.f; }
  uint_t pk = ((uint_t)f32_to_bf16_rne(ew) << 16) | sl;
  edata[(size_t)tg * RST + rk] = pk;
}

// ---------------------------------------------------------------------------
// dinv[i] = 1/sqrt(deg+1), deg = sum of packed bf16 ew over the node's row.
// ---------------------------------------------------------------------------
__global__ __launch_bounds__(256) void dinv_kernel(
    const uint_t* __restrict__ edata, const int* __restrict__ cntp,
    float* __restrict__ dinv) {
  int i = blockIdx.x * 256 + threadIdx.x;
  if (i >= T) return;
  int cnt = cntp[(size_t)i * PAD];
  cnt = (cnt > RST) ? RST : cnt;
  const uint_t* row = edata + (size_t)i * RST;
  float s = 0.f;
  for (int j = 0; j < cnt; ++j) s += bf16_to_f32((ushort_t)(row[j] >> 16));
  dinv[i] = 1.0f / sqrtf(s + 1.0f);
}

// ---------------------------------------------------------------------------
// MFMA GEMM with in-register x->bf16 hi/lo split (no staging round-trip).
// Wave = 32 rows x 64 cols (2 n-tiles, 48 MFMAs); 563 blocks, 2.2 waves/SIMD.
// Convert = ~192 VALU cyc/wave vs 384 MFMA cyc -> hidden via wave overlap.
// A/B frag: elem = lane&31, k = 8*(lane>>5)+j. C/D: col = lane&31,
// row = (j&3)+8*(j>>2)+4*(lane>>5).
// ---------------------------------------------------------------------------
__global__ __launch_bounds__(256) void gemm_kernel(
    const float* __restrict__ x, const ushort_t* __restrict__ Whi,
    const ushort_t* __restrict__ Wlo, const float* __restrict__ bias,
    float* __restrict__ h) {
  const int g = blockIdx.x * 4 + (threadIdx.x >> 6);
  if (g >= (T / 32) * 2) return;
  const int lane = threadIdx.x & 63;
  const int mt = g >> 1;          // row-tile
  const int nh = g & 1;           // col-half (64 cols)
  const int m0 = mt * 32;
  const int r  = lane & 31;
  const int kh = lane >> 5;

  const float* xrow = x + (size_t)(m0 + r) * D + kh * 8;

  f32x16 acc[2];
#pragma unroll
  for (int n = 0; n < 2; ++n)
#pragma unroll
    for (int j = 0; j < 16; ++j) acc[n][j] = 0.f;

#pragma unroll
  for (int ks = 0; ks < 8; ++ks) {
    const float4 p0 = ((const float4*)(xrow + ks * 16))[0];
    const float4 p1 = ((const float4*)(xrow + ks * 16))[1];
    const float xa[8] = {p0.x, p0.y, p0.z, p0.w, p1.x, p1.y, p1.z, p1.w};
    bf16x8 ahi, alo;
#pragma unroll
    for (int j = 0; j < 8; ++j) {
      ushort_t hb = f32_to_bf16_rne(xa[j]);
      ahi[j] = (short)hb;
      alo[j] = (short)f32_to_bf16_rne(xa[j] - bf16_to_f32(hb));
    }
#pragma unroll
    for (int n = 0; n < 2; ++n) {
      const size_t boff = (size_t)((nh * 2 + n) * 32 + r) * D + ks * 16 + kh * 8;
      bf16x8 bhi = *(const bf16x8*)(Whi + boff);
      bf16x8 blo = *(const bf16x8*)(Wlo + boff);
      acc[n] = __builtin_amdgcn_mfma_f32_32x32x16_bf16(ahi, bhi, acc[n], 0, 0, 0);
      acc[n] = __builtin_amdgcn_mfma_f32_32x32x16_bf16(ahi, blo, acc[n], 0, 0, 0);
      acc[n] = __builtin_amdgcn_mfma_f32_32x32x16_bf16(alo, bhi, acc[n], 0, 0, 0);
    }
  }

#pragma unroll
  for (int n = 0; n < 2; ++n) {
    const int col = (nh * 2 + n) * 32 + r;
    const float bv = bias[col];
#pragma unroll
    for (int j = 0; j < 16; ++j) {
      const int mrow = m0 + (j & 3) + 8 * (j >> 2) + 4 * kh;
      h[(size_t)mrow * D + col] = acc[n][j] + bv;
    }
  }
}

// ---------------------------------------------------------------------------
// Fused gather + residual + LayerNorm + ReLU + mask (packed edata).
// XCD-pinned: bid%8 = batch (h slice 2.3MB -> per-XCD L2). 32 lanes x float4
// per row; lane-half processes alternating slots; fold via shfl_xor(32).
// ---------------------------------------------------------------------------
__global__ __launch_bounds__(256) void gather_ln_kernel(
    const float* __restrict__ h, const int* __restrict__ cntp,
    const uint_t* __restrict__ edata, const float* __restrict__ dinv,
    const float* __restrict__ gamma, const float* __restrict__ beta,
    const float* __restrict__ mask, float* __restrict__ out) {
  const int bid  = blockIdx.x;                  // 9000 = 8 * 1125
  const int b    = bid & 7;
  const int wid  = threadIdx.x >> 6;
  const int node = b * Nn + (bid >> 3) * 4 + wid;
  const int bOff = b * Nn;
  const int lane = threadIdx.x & 63;
  const int f4   = lane & 31;
  const int half = lane >> 5;

  const float4* h4 = (const float4*)h;
  int cnt = cntp[(size_t)node * PAD];
  cnt = (cnt > RST) ? RST : cnt;
  const uint_t* row = edata + (size_t)node * RST;

  float4 hv = h4[(size_t)node * 32 + f4];

  float4 accE = make_float4(0.f, 0.f, 0.f, 0.f);
  int i = half;
  for (; i + 6 < cnt; i += 8) {
    uint_t p0 = row[i];
    uint_t p1 = row[i + 2];
    uint_t p2 = row[i + 4];
    uint_t p3 = row[i + 6];
    int sg0 = bOff + (p0 & 0xFFFFu);
    int sg1 = bOff + (p1 & 0xFFFFu);
    int sg2 = bOff + (p2 & 0xFFFFu);
    int sg3 = bOff + (p3 & 0xFFFFu);
    float c0 = dinv[sg0] * bf16_to_f32((ushort_t)(p0 >> 16));
    float c1 = dinv[sg1] * bf16_to_f32((ushort_t)(p1 >> 16));
    float c2 = dinv[sg2] * bf16_to_f32((ushort_t)(p2 >> 16));
    float c3 = dinv[sg3] * bf16_to_f32((ushort_t)(p3 >> 16));
    float4 v0 = h4[(size_t)sg0 * 32 + f4];
    float4 v1 = h4[(size_t)sg1 * 32 + f4];
    float4 v2 = h4[(size_t)sg2 * 32 + f4];
    float4 v3 = h4[(size_t)sg3 * 32 + f4];
    accE.x += v0.x * c0 + v1.x * c1 + v2.x * c2 + v3.x * c3;
    accE.y += v0.y * c0 + v1.y * c1 + v2.y * c2 + v3.y * c3;
    accE.z += v0.z * c0 + v1.z * c1 + v2.z * c2 + v3.z * c3;
    accE.w += v0.w * c0 + v1.w * c1 + v2.w * c2 + v3.w * c3;
  }
  for (; i < cnt; i += 2) {
    uint_t p0 = row[i];
    int sg0 = bOff + (p0 & 0xFFFFu);
    float c0 = dinv[sg0] * bf16_to_f32((ushort_t)(p0 >> 16));
    float4 v0 = h4[(size_t)sg0 * 32 + f4];
    accE.x += v0.x * c0;
    accE.y += v0.y * c0;
    accE.z += v0.z * c0;
    accE.w += v0.w * c0;
  }

  accE.x += __shfl_xor(accE.x, 32);
  accE.y += __shfl_xor(accE.y, 32);
  accE.z += __shfl_xor(accE.z, 32);
  accE.w += __shfl_xor(accE.w, 32);

  const float dt = dinv[node];
  float4 acc;
  acc.x = hv.x * (1.f + dt) + dt * accE.x;
  acc.y = hv.y * (1.f + dt) + dt * accE.y;
  acc.z = hv.z * (1.f + dt) + dt * accE.z;
  acc.w = hv.w * (1.f + dt) + dt * accE.w;

  float su = acc.x + acc.y + acc.z + acc.w;
  float ss = acc.x * acc.x + acc.y * acc.y + acc.z * acc.z + acc.w * acc.w;
#pragma unroll
  for (int o = 16; o > 0; o >>= 1) {
    su += __shfl_xor(su, o);
    ss += __shfl_xor(ss, o);
  }
  float mu  = su * (1.0f / 128.0f);
  float var = ss * (1.0f / 128.0f) - mu * mu;
  float rs  = 1.0f / sqrtf(var + EPS);
  float m   = mask[node];

  float4 g  = ((const float4*)gamma)[f4];
  float4 bb = ((const float4*)beta)[f4];
  float4 rv;
  rv.x = fmaxf((acc.x - mu) * rs * g.x + bb.x, 0.f) * m;
  rv.y = fmaxf((acc.y - mu) * rs * g.y + bb.y, 0.f) * m;
  rv.z = fmaxf((acc.z - mu) * rs * g.z + bb.z, 0.f) * m;
  rv.w = fmaxf((acc.w - mu) * rs * g.w + bb.w, 0.f) * m;
  if (half == 0) ((float4*)out)[(size_t)node * 32 + f4] = rv;
}

// ---------------------------------------------------------------------------
extern "C" void kernel_launch(void* const* d_in, const int* in_sizes, int n_in,
                              void* d_out, int out_size, void* d_ws, size_t ws_size,
                              hipStream_t stream) {
  const float* x     = (const float*)d_in[0];
  const int*   ei    = (const int*)d_in[1];
  const float* nmask = (const float*)d_in[2];
  const float* emask = (const float*)d_in[3];
  const float* W     = (const float*)d_in[4];
  const float* bias  = (const float*)d_in[5];
  const float* gamma = (const float*)d_in[6];
  const float* beta  = (const float*)d_in[7];
  float* out = (float*)d_out;

  char*     ws    = (char*)d_ws;
  int*      cntp  = (int*)     (ws + WS_CNTP);
  uint_t*   edata = (uint_t*)  (ws + WS_EDATA);
  float*    dinv  = (float*)   (ws + WS_DINV);
  ushort_t* Whi   = (ushort_t*)(ws + WS_WHI);
  ushort_t* Wlo   = (ushort_t*)(ws + WS_WLO);
  float*    h     = (float*)   (ws + WS_H);

  prep_kernel<<<NB_PREP, 256, 0, stream>>>(W, Whi, Wlo, (int4*)cntp);
  edge_kernel<<<NB_EDGE, 256, 0, stream>>>(ei, emask, cntp, edata);
  dinv_kernel<<<(T + 255) / 256, 256, 0, stream>>>(edata, cntp, dinv);
  gemm_kernel<<<NB_GEMM, 256, 0, stream>>>(x, Whi, Wlo, bias, h);
  gather_ln_kernel<<<T / 4, 256, 0, stream>>>(h, cntp, edata, dinv,
                                              gamma, beta, nmask, out);
}

// Round 14
// 81.217 us; speedup vs baseline: 1.3033x; 1.0777x over previous
//
#include <hip/hip_runtime.h>
#include <math.h>

typedef unsigned short ushort_t;
typedef unsigned int uint_t;
typedef __attribute__((ext_vector_type(8))) short bf16x8;
typedef __attribute__((ext_vector_type(16))) float f32x16;

// Problem constants (from reference)
constexpr int Bc   = 8;
constexpr int Nn   = 4500;
constexpr int Ec   = 72000;
constexpr int D    = 128;          // IN_DIM == OUT_DIM == 128
constexpr int T    = Bc * Nn;      // 36000 total nodes
constexpr int TE   = Bc * Ec;      // 576000 total edges
constexpr float EPS = 1e-5f;

constexpr int PAD = 32;            // ints per counter line (128B)
constexpr int RST = 64;            // edata slots per node (max deg ~45), 4B each

// Prep zones: W split | cntp zero
constexpr int NB_W    = 64;                    // 16384 W elems / 256
constexpr int NB_Z    = (T * PAD / 4) / 256;   // 1125 (int4 zero)
constexpr int NB_PREP = NB_W + NB_Z;           // 1189

// Edge pass: XCD-pinned, 8 batches x 282 chunks
constexpr int NB_ECH  = (Ec + 255) / 256;      // 282
constexpr int NB_EDGE = 8 * NB_ECH;            // 2256

// gemm+dinv zones
constexpr int NB_GEMM = ((T / 32) * 2 + 3) / 4;   // 563
constexpr int NB_DINV = 8 * 18;                   // XCD-pinned, 8 x 18 x 256 = 36864
constexpr int NB_GD   = NB_GEMM + NB_DINV;        // 707

// Workspace layout (bytes), ~23.3 MB total.
constexpr size_t WS_CNTP  = 0;            // T*PAD i32 = 4,608,000
constexpr size_t WS_EDATA = 4608000;      // T*RST u32 = 9,216,000
constexpr size_t WS_DINV  = 13824000;     // T f32 = 144,000
constexpr size_t WS_WHI   = 13968000;     // 128*128 bf16 = 32,768
constexpr size_t WS_WLO   = 14000768;     // 128*128 bf16 = 32,768
constexpr size_t WS_H     = 14033536;     // T*D bf16 = 9,216,000

__device__ __forceinline__ ushort_t f32_to_bf16_rne(float f) {
  uint_t u = __float_as_uint(f);
  uint_t r = (u + 0x7fffu + ((u >> 16) & 1u)) >> 16;
  return (ushort_t)r;
}
__device__ __forceinline__ float bf16_to_f32(ushort_t h) {
  return __uint_as_float(((uint_t)h) << 16);
}

// ---------------------------------------------------------------------------
// Prep (zoned): [0,64) W -> bf16 hi/lo; [64,1189) zero cntp (int4).
// ---------------------------------------------------------------------------
__global__ __launch_bounds__(256) void prep_kernel(
    const float* __restrict__ W, ushort_t* __restrict__ Whi,
    ushort_t* __restrict__ Wlo, int4* __restrict__ cntp4) {
  const int bid = blockIdx.x;
  if (bid < NB_W) {
    int i = bid * 256 + threadIdx.x;
    float w = W[i];
    ushort_t hi = f32_to_bf16_rne(w);
    Whi[i] = hi;
    Wlo[i] = f32_to_bf16_rne(w - bf16_to_f32(hi));
  } else {
    int i = (bid - NB_W) * 256 + threadIdx.x;
    cntp4[i] = make_int4(0, 0, 0, 0);
  }
}

// ---------------------------------------------------------------------------
// Edge pass (XCD-pinned: bid&7 = batch): rk = fetch-add on padded counter;
// packed placement edata[tgt*RST+rk] = bf16(ew)<<16 | src_local (4B).
// ---------------------------------------------------------------------------
__global__ __launch_bounds__(256) void edge_kernel(
    const int* __restrict__ ei, const float* __restrict__ em,
    int* __restrict__ cntp, uint_t* __restrict__ edata) {
  const int b  = blockIdx.x & 7;
  const int el = (blockIdx.x >> 3) * 256 + threadIdx.x;
  if (el >= Ec) return;
  const int* eb = ei + b * 2 * Ec;
  int t0 = eb[Ec + el];
  if ((unsigned)t0 >= (unsigned)Nn) return;     // defensive
  int tg = t0 + b * Nn;
  int rk = atomicAdd(&cntp[(size_t)tg * PAD], 1);
  if (rk >= RST) return;                        // defensive (P ~ 0)
  int s0 = eb[el];
  float ew = em[b * Ec + el];
  uint_t sl = (uint_t)s0;
  if ((unsigned)s0 >= (unsigned)Nn) { sl = 0; ew = 0.f; }
  uint_t pk = ((uint_t)f32_to_bf16_rne(ew) << 16) | sl;
  edata[(size_t)tg * RST + rk] = pk;
}

// ---------------------------------------------------------------------------
// Zone-merged: [0,563) MFMA GEMM (bf16 h out); [563,707) dinv (XCD-pinned).
// GEMM: wave = 32 rows x 64 cols, in-register x->bf16 hi/lo split, 48 MFMAs.
// A/B frag: elem = lane&31, k = 8*(lane>>5)+j. C/D: col = lane&31,
// row = (j&3)+8*(j>>2)+4*(lane>>5).
// dinv zone is memory-light (unlike R11's edge zone) -> co-schedule is safe.
// ---------------------------------------------------------------------------
__global__ __launch_bounds__(256) void gemm_dinv_kernel(
    const float* __restrict__ x, const ushort_t* __restrict__ Whi,
    const ushort_t* __restrict__ Wlo, const float* __restrict__ bias,
    ushort_t* __restrict__ h, const uint_t* __restrict__ edata,
    const int* __restrict__ cntp, float* __restrict__ dinv) {
  const int bid = blockIdx.x;
  if (bid < NB_GEMM) {
    const int g = bid * 4 + (threadIdx.x >> 6);
    if (g >= (T / 32) * 2) return;
    const int lane = threadIdx.x & 63;
    const int mt = g >> 1;          // row-tile
    const int nh = g & 1;           // col-half (64 cols)
    const int m0 = mt * 32;
    const int r  = lane & 31;
    const int kh = lane >> 5;

    const float* xrow = x + (size_t)(m0 + r) * D + kh * 8;

    f32x16 acc[2];
#pragma unroll
    for (int n = 0; n < 2; ++n)
#pragma unroll
      for (int j = 0; j < 16; ++j) acc[n][j] = 0.f;

#pragma unroll
    for (int ks = 0; ks < 8; ++ks) {
      const float4 p0 = ((const float4*)(xrow + ks * 16))[0];
      const float4 p1 = ((const float4*)(xrow + ks * 16))[1];
      const float xa[8] = {p0.x, p0.y, p0.z, p0.w, p1.x, p1.y, p1.z, p1.w};
      bf16x8 ahi, alo;
#pragma unroll
      for (int j = 0; j < 8; ++j) {
        ushort_t hb = f32_to_bf16_rne(xa[j]);
        ahi[j] = (short)hb;
        alo[j] = (short)f32_to_bf16_rne(xa[j] - bf16_to_f32(hb));
      }
#pragma unroll
      for (int n = 0; n < 2; ++n) {
        const size_t boff = (size_t)((nh * 2 + n) * 32 + r) * D + ks * 16 + kh * 8;
        bf16x8 bhi = *(const bf16x8*)(Whi + boff);
        bf16x8 blo = *(const bf16x8*)(Wlo + boff);
        acc[n] = __builtin_amdgcn_mfma_f32_32x32x16_bf16(ahi, bhi, acc[n], 0, 0, 0);
        acc[n] = __builtin_amdgcn_mfma_f32_32x32x16_bf16(ahi, blo, acc[n], 0, 0, 0);
        acc[n] = __builtin_amdgcn_mfma_f32_32x32x16_bf16(alo, bhi, acc[n], 0, 0, 0);
      }
    }

#pragma unroll
    for (int n = 0; n < 2; ++n) {
      const int col = (nh * 2 + n) * 32 + r;
      const float bv = bias[col];
#pragma unroll
      for (int j = 0; j < 16; ++j) {
        const int mrow = m0 + (j & 3) + 8 * (j >> 2) + 4 * kh;
        h[(size_t)mrow * D + col] = f32_to_bf16_rne(acc[n][j] + bv);
      }
    }
  } else {
    // dinv zone, XCD-pinned: batch = (bid-NB_GEMM)&7
    const int zb = bid - NB_GEMM;
    const int b  = zb & 7;
    const int nl = (zb >> 3) * 256 + threadIdx.x;
    if (nl >= Nn) return;
    const int i = b * Nn + nl;
    int cnt = cntp[(size_t)i * PAD];
    cnt = (cnt > RST) ? RST : cnt;
    const uint_t* row = edata + (size_t)i * RST;
    float s = 0.f;
    for (int j = 0; j < cnt; ++j) s += bf16_to_f32((ushort_t)(row[j] >> 16));
    dinv[i] = 1.0f / sqrtf(s + 1.0f);
  }
}

// ---------------------------------------------------------------------------
// Fused gather + residual + LayerNorm + ReLU + mask (packed edata, bf16 h).
// XCD-pinned: bid%8 = batch (h slice 1.15MB -> per-XCD L2). 32 lanes x 4
// features per row; lane-half processes alternating slots; fold shfl_xor(32).
// ---------------------------------------------------------------------------
__global__ __launch_bounds__(256) void gather_ln_kernel(
    const ushort_t* __restrict__ h, const int* __restrict__ cntp,
    const uint_t* __restrict__ edata, const float* __restrict__ dinv,
    const float* __restrict__ gamma, const float* __restrict__ beta,
    const float* __restrict__ mask, float* __restrict__ out) {
  const int bid  = blockIdx.x;                  // 9000 = 8 * 1125
  const int b    = bid & 7;
  const int wid  = threadIdx.x >> 6;
  const int node = b * Nn + (bid >> 3) * 4 + wid;
  const int bOff = b * Nn;
  const int lane = threadIdx.x & 63;
  const int f4   = lane & 31;
  const int half = lane >> 5;

  const ushort4* h4 = (const ushort4*)h;
  int cnt = cntp[(size_t)node * PAD];
  cnt = (cnt > RST) ? RST : cnt;
  const uint_t* row = edata + (size_t)node * RST;

  ushort4 hq = h4[(size_t)node * 32 + f4];
  float4 hv = make_float4(bf16_to_f32(hq.x), bf16_to_f32(hq.y),
                          bf16_to_f32(hq.z), bf16_to_f32(hq.w));

  float4 accE = make_float4(0.f, 0.f, 0.f, 0.f);
  int i = half;
  for (; i + 6 < cnt; i += 8) {
    uint_t p0 = row[i];
    uint_t p1 = row[i + 2];
    uint_t p2 = row[i + 4];
    uint_t p3 = row[i + 6];
    int sg0 = bOff + (p0 & 0xFFFFu);
    int sg1 = bOff + (p1 & 0xFFFFu);
    int sg2 = bOff + (p2 & 0xFFFFu);
    int sg3 = bOff + (p3 & 0xFFFFu);
    float c0 = dinv[sg0] * bf16_to_f32((ushort_t)(p0 >> 16));
    float c1 = dinv[sg1] * bf16_to_f32((ushort_t)(p1 >> 16));
    float c2 = dinv[sg2] * bf16_to_f32((ushort_t)(p2 >> 16));
    float c3 = dinv[sg3] * bf16_to_f32((ushort_t)(p3 >> 16));
    ushort4 q0 = h4[(size_t)sg0 * 32 + f4];
    ushort4 q1 = h4[(size_t)sg1 * 32 + f4];
    ushort4 q2 = h4[(size_t)sg2 * 32 + f4];
    ushort4 q3 = h4[(size_t)sg3 * 32 + f4];
    accE.x += bf16_to_f32(q0.x) * c0 + bf16_to_f32(q1.x) * c1 +
              bf16_to_f32(q2.x) * c2 + bf16_to_f32(q3.x) * c3;
    accE.y += bf16_to_f32(q0.y) * c0 + bf16_to_f32(q1.y) * c1 +
              bf16_to_f32(q2.y) * c2 + bf16_to_f32(q3.y) * c3;
    accE.z += bf16_to_f32(q0.z) * c0 + bf16_to_f32(q1.z) * c1 +
              bf16_to_f32(q2.z) * c2 + bf16_to_f32(q3.z) * c3;
    accE.w += bf16_to_f32(q0.w) * c0 + bf16_to_f32(q1.w) * c1 +
              bf16_to_f32(q2.w) * c2 + bf16_to_f32(q3.w) * c3;
  }
  for (; i < cnt; i += 2) {
    uint_t p0 = row[i];
    int sg0 = bOff + (p0 & 0xFFFFu);
    float c0 = dinv[sg0] * bf16_to_f32((ushort_t)(p0 >> 16));
    ushort4 q0 = h4[(size_t)sg0 * 32 + f4];
    accE.x += bf16_to_f32(q0.x) * c0;
    accE.y += bf16_to_f32(q0.y) * c0;
    accE.z += bf16_to_f32(q0.z) * c0;
    accE.w += bf16_to_f32(q0.w) * c0;
  }

  accE.x += __shfl_xor(accE.x, 32);
  accE.y += __shfl_xor(accE.y, 32);
  accE.z += __shfl_xor(accE.z, 32);
  accE.w += __shfl_xor(accE.w, 32);

  const float dt = dinv[node];
  float4 acc;
  acc.x = hv.x * (1.f + dt) + dt * accE.x;
  acc.y = hv.y * (1.f + dt) + dt * accE.y;
  acc.z = hv.z * (1.f + dt) + dt * accE.z;
  acc.w = hv.w * (1.f + dt) + dt * accE.w;

  float su = acc.x + acc.y + acc.z + acc.w;
  float ss = acc.x * acc.x + acc.y * acc.y + acc.z * acc.z + acc.w * acc.w;
#pragma unroll
  for (int o = 16; o > 0; o >>= 1) {
    su += __shfl_xor(su, o);
    ss += __shfl_xor(ss, o);
  }
  float mu  = su * (1.0f / 128.0f);
  float var = ss * (1.0f / 128.0f) - mu * mu;
  float rs  = 1.0f / sqrtf(var + EPS);
  float m   = mask[node];

  float4 g  = ((const float4*)gamma)[f4];
  float4 bb = ((const float4*)beta)[f4];
  float4 rv;
  rv.x = fmaxf((acc.x - mu) * rs * g.x + bb.x, 0.f) * m;
  rv.y = fmaxf((acc.y - mu) * rs * g.y + bb.y, 0.f) * m;
  rv.z = fmaxf((acc.z - mu) * rs * g.z + bb.z, 0.f) * m;
  rv.w = fmaxf((acc.w - mu) * rs * g.w + bb.w, 0.f) * m;
  if (half == 0) ((float4*)out)[(size_t)node * 32 + f4] = rv;
}

// ---------------------------------------------------------------------------
extern "C" void kernel_launch(void* const* d_in, const int* in_sizes, int n_in,
                              void* d_out, int out_size, void* d_ws, size_t ws_size,
                              hipStream_t stream) {
  const float* x     = (const float*)d_in[0];
  const int*   ei    = (const int*)d_in[1];
  const float* nmask = (const float*)d_in[2];
  const float* emask = (const float*)d_in[3];
  const float* W     = (const float*)d_in[4];
  const float* bias  = (const float*)d_in[5];
  const float* gamma = (const float*)d_in[6];
  const float* beta  = (const float*)d_in[7];
  float* out = (float*)d_out;

  char*     ws    = (char*)d_ws;
  int*      cntp  = (int*)     (ws + WS_CNTP);
  uint_t*   edata = (uint_t*)  (ws + WS_EDATA);
  float*    dinv  = (float*)   (ws + WS_DINV);
  ushort_t* Whi   = (ushort_t*)(ws + WS_WHI);
  ushort_t* Wlo   = (ushort_t*)(ws + WS_WLO);
  ushort_t* h     = (ushort_t*)(ws + WS_H);

  prep_kernel<<<NB_PREP, 256, 0, stream>>>(W, Whi, Wlo, (int4*)cntp);
  edge_kernel<<<NB_EDGE, 256, 0, stream>>>(ei, emask, cntp, edata);
  gemm_dinv_kernel<<<NB_GD, 256, 0, stream>>>(x, Whi, Wlo, bias, h,
                                              edata, cntp, dinv);
  gather_ln_kernel<<<T / 4, 256, 0, stream>>>(h, cntp, edata, dinv,
                                              gamma, beta, nmask, out);
}